// Round 1
// baseline (133.111 us; speedup 1.0000x reference)
//
#include <hip/hip_runtime.h>

// Nearest-neighbor 2x upsample, fp32.
// Input:  [B=16, C=128, H=128, W=128]
// Output: [B=16, C=128, 2H=256, 2W=256]
//
// Each thread handles 2 adjacent input columns of one row:
//   load float2 {x, y}  -> store float4 {x, x, y, y} to out rows 2h and 2h+1.
// Reads: 8 B/lane coalesced. Writes: 2 x 16 B/lane, each store instruction
// contiguous across the wave (lane i writes bytes [16i, 16i+16)).

#define H_IN   128
#define W_IN   128
#define H_OUT  256
#define W_OUT  256
#define WPAIRS (W_IN / 2)   // 64 float2 pairs per input row

__global__ __launch_bounds__(256) void nn_upsample2x_kernel(
    const float* __restrict__ in, float* __restrict__ out, int total_pairs) {
    int stride = gridDim.x * blockDim.x;
    for (int t = blockIdx.x * blockDim.x + threadIdx.x; t < total_pairs; t += stride) {
        int jq  = t & (WPAIRS - 1);      // pair index within row: 0..63
        int row = t >> 6;                // global input row: b*C*H + c*H + h
        int h   = row & (H_IN - 1);
        int bc  = row >> 7;              // b*C + c

        const float2 v = *reinterpret_cast<const float2*>(in + (size_t)row * W_IN + jq * 2);
        float4 w;
        w.x = v.x; w.y = v.x; w.z = v.y; w.w = v.y;

        size_t obase = ((size_t)bc * H_OUT + 2 * h) * W_OUT + jq * 4;
        *reinterpret_cast<float4*>(out + obase)         = w;  // out row 2h
        *reinterpret_cast<float4*>(out + obase + W_OUT) = w;  // out row 2h+1
    }
}

extern "C" void kernel_launch(void* const* d_in, const int* in_sizes, int n_in,
                              void* d_out, int out_size, void* d_ws, size_t ws_size,
                              hipStream_t stream) {
    const float* in  = (const float*)d_in[0];
    float*       out = (float*)d_out;

    // total input pairs = B*C*H * (W/2) = 16*128*128*64 = 16,777,216
    int total_pairs = in_sizes[0] / 2;

    const int block = 256;
    const int grid  = 8192;  // grid-stride: ~8 iterations/thread
    nn_upsample2x_kernel<<<grid, block, 0, stream>>>(in, out, total_pairs);
}